// Round 16
// baseline (295.514 us; speedup 1.0000x reference)
//
#include <hip/hip_runtime.h>
#include <hip/hip_bf16.h>
#include <math.h>

#define NN 2048           // x is 2048 x 2048 (DP grid = [0,2046]^2)
#define TROWS 1040        // table rows per half (1024 + prefetch margin)
#define NW 4              // 4 waves per WG (1 per SIMD), CPL=8
#define RPS 32            // rows per wave per step (32-row cadence: ~57 nats << 88)
#define LN2 0.6931471805599453

// d_ws layout (floats): tab[TROWS][NN] | tabR[TROWS][NN] | arr: S,tg,yc,gM,gY (5*NN) | res (4 words)

__global__ void prep_kernel(const float* __restrict__ x, float* __restrict__ tab,
                            float* __restrict__ tabR) {
  const int c = blockIdx.x * 256 + threadIdx.x;
  const int t = blockIdx.y;
  tab[(size_t)t * NN + c] = __expf(x[(size_t)t * NN + c]);
  const int rr = 2048 - t, cc = 2048 - c;
  float v = 0.f;
  if (rr < 2048 && cc < 2048) v = __expf(x[(size_t)rr * NN + cc]);
  tabR[(size_t)t * NN + c] = v;
}

// ---------------------------------------------------------------------------
// R16 = R14's proven machinery at NW=4 / CPL=8: amortizes the per-wave fixed
// cost (3 shuffles, edge r/w, Q-chain, loop) over 8 columns, halves DS-pipe
// traffic, and cuts skew drain 7->3 steps. Seed truncation improves to e^-16
// (C8). Named scalar carries only (rule #20). Same parity-LDS edges, shared
// pow2 exponent per 32 rows, bidirectional fwd/adjoint split, combine.
// ---------------------------------------------------------------------------
template<int MODE>
__global__ __launch_bounds__(NW * 64)
void sw2_kernel(const float* __restrict__ x, const float* __restrict__ tab,
                const float* __restrict__ tabR, float* __restrict__ arr,
                float* __restrict__ out) {
  const int tid  = threadIdx.x;
  const int lane = tid & 63;
  const int wv   = __builtin_amdgcn_readfirstlane(tid >> 6);   // 0..3
  const int c0   = (wv << 9) + lane * 8;

  __shared__ float2 E[2][NW + 1][RPS];   // [parity][wave+1][row]; wave-0 input = zeros
  __shared__ float  red[2][NW];
  __shared__ float  wsum[NW];

  for (int i = tid; i < 2 * (NW + 1) * RPS; i += NW * 64)
    ((float2*)E)[i] = make_float2(0.f, 0.f);
  __syncthreads();

  const float cGO = 0.006737946999085467f;   // e^-5
  const float cGE = 0.36787944117144233f;    // e^-1
  const float C8  = 0.00033546262790251185f; // e^-8
  const bool isL0 = (lane == 0), isL1 = (lane == 1), isL63 = (lane == 63);

  if (MODE == 0 || blockIdx.x == 0) {
    // ======================= FORWARD =======================
    const int SPW   = ((MODE == 0) ? 2048 : 1024) / RPS;
    const int NSTEP = SPW + NW - 1;
    float s1_0=0.f,s1_1=0.f,s1_2=0.f,s1_3=0.f,s1_4=0.f,s1_5=0.f,s1_6=0.f,s1_7=0.f;
    float tg0=0.f,tg1=0.f,tg2=0.f,tg3=0.f,tg4=0.f,tg5=0.f,tg6=0.f,tg7=0.f;
    float yc0=0.f,yc1=0.f,yc2=0.f,yc3=0.f,yc4=0.f,yc5=0.f,yc6=0.f,yc7=0.f;
    float acc=0.f, one=1.f, tmx=0.f, escale=1.f, SinC=0.f;
    int Etot = 0;
    const float* src = ((MODE == 0) ? x : tab) + c0;
    float4 pA0 = *(const float4*)(src),          pA1 = *(const float4*)(src + 4);
    float4 pB0 = *(const float4*)(src + NN),     pB1 = *(const float4*)(src + NN + 4);
    float4 pC0 = *(const float4*)(src + 2 * NN), pC1 = *(const float4*)(src + 2 * NN + 4);
    float4 pD0 = *(const float4*)(src + 3 * NN), pD1 = *(const float4*)(src + 3 * NN + 4);
    const float* pl = src + 4 * NN;
    int rown = 4;

    int cr_ = 0, pr_ = 0;
    float prevEdx = 0.f;
    auto rowF = [&](float4 v0, float4 v1, int k, bool first) {
      float e0 = v0.x, e1 = v0.y, e2 = v0.z, e3 = v0.w;
      float e4 = v1.x, e5 = v1.y, e6 = v1.z, e7 = v1.w;
      if (MODE == 0) {
        e0 = __expf(e0); e1 = __expf(e1); e2 = __expf(e2); e3 = __expf(e3);
        e4 = __expf(e4); e5 = __expf(e5); e6 = __expf(e6); e7 = __expf(e7);
      }
      const float2 edc = E[cr_][wv][k];
      const float Sr = first ? SinC : prevEdx * escale;
      const float Xi = edc.y * escale;
      prevEdx = edc.x;

      float sh  = __shfl_up(s1_7, 1);
      float sd0 = isL0 ? Sr : sh;
      acc = fmaf(e0, sd0,  acc); acc = fmaf(e1, s1_0, acc);
      acc = fmaf(e2, s1_1, acc); acc = fmaf(e3, s1_2, acc);
      acc = fmaf(e4, s1_3, acc); acc = fmaf(e5, s1_4, acc);
      acc = fmaf(e6, s1_5, acc); acc = fmaf(e7, s1_6, acc);
      float M0 = e0 * (sd0  + one);
      float M1 = e1 * (s1_0 + one);
      float M2 = e2 * (s1_1 + one);
      float M3 = e3 * (s1_2 + one);
      float M4 = e4 * (s1_3 + one);
      float M5 = e5 * (s1_4 + one);
      float M6 = e6 * (s1_5 + one);
      float M7 = e7 * (s1_6 + one);

      float Q = fmaf(cGE, fmaf(cGE, fmaf(cGE, fmaf(cGE, fmaf(cGE, fmaf(cGE,
                fmaf(cGE, M0, M1), M2), M3), M4), M5), M6), M7);
      float q1 = __shfl_up(Q, 1);
      float q2 = __shfl_up(Q, 2);
      q2 = isL1 ? Xi : q2;
      float X0 = fmaf(C8, q2, q1);
      X0 = isL0 ? Xi : X0;
      float X1 = fmaf(cGE, X0, M0);
      float X2 = fmaf(cGE, X1, M1);
      float X3 = fmaf(cGE, X2, M2);
      float X4 = fmaf(cGE, X3, M3);
      float X5 = fmaf(cGE, X4, M4);
      float X6 = fmaf(cGE, X5, M5);
      float X7 = fmaf(cGE, X6, M6);

      float T0 = fmaf(cGO, X0, M0);
      float T1 = fmaf(cGO, X1, M1);
      float T2 = fmaf(cGO, X2, M2);
      float T3 = fmaf(cGO, X3, M3);
      float T4 = fmaf(cGO, X4, M4);
      float T5 = fmaf(cGO, X5, M5);
      float T6 = fmaf(cGO, X6, M6);
      float T7 = fmaf(cGO, X7, M7);
      float Y0 = fmaf(cGE, yc0, tg0);
      float Y1 = fmaf(cGE, yc1, tg1);
      float Y2 = fmaf(cGE, yc2, tg2);
      float Y3 = fmaf(cGE, yc3, tg3);
      float Y4 = fmaf(cGE, yc4, tg4);
      float Y5 = fmaf(cGE, yc5, tg5);
      float Y6 = fmaf(cGE, yc6, tg6);
      float Y7 = fmaf(cGE, yc7, tg7);
      float S0 = T0 + Y0, S1n = T1 + Y1, S2n = T2 + Y2, S3n = T3 + Y3;
      float S4n = T4 + Y4, S5n = T5 + Y5, S6n = T6 + Y6, S7n = T7 + Y7;
      tmx = fmaxf(tmx, fmaxf(fmaxf(fmaxf(S0, S1n), fmaxf(S2n, S3n)),
                             fmaxf(fmaxf(S4n, S5n), fmaxf(S6n, S7n))));
      tg0 = cGO * T0; tg1 = cGO * T1; tg2 = cGO * T2; tg3 = cGO * T3;
      tg4 = cGO * T4; tg5 = cGO * T5; tg6 = cGO * T6; tg7 = cGO * T7;
      yc0 = Y0; yc1 = Y1; yc2 = Y2; yc3 = Y3;
      yc4 = Y4; yc5 = Y5; yc6 = Y6; yc7 = Y7;
      s1_0 = S0; s1_1 = S1n; s1_2 = S2n; s1_3 = S3n;
      s1_4 = S4n; s1_5 = S5n; s1_6 = S6n; s1_7 = S7n;

      if (isL63) E[pr_][wv + 1][k] = make_float2(S7n, fmaf(C8, X0, Q));
    };

    for (int s = 0; s < NSTEP; ++s) {
      pr_ = s & 1; cr_ = pr_ ^ 1;
      const bool act = (s >= wv) && (s < wv + SPW);
      if (act) {
        prevEdx = 0.f;
        for (int kk = 0; kk < RPS / 4; ++kk) {
          const int kb = kk << 2;
          float4 a0 = pA0, a1 = pA1, b0 = pB0, b1 = pB1;
          float4 c0v = pC0, c1v = pC1, d0 = pD0, d1 = pD1;
          if (MODE == 1) {
            pA0 = *(const float4*)pl; pA1 = *(const float4*)(pl + 4); pl += NN;
            pB0 = *(const float4*)pl; pB1 = *(const float4*)(pl + 4); pl += NN;
            pC0 = *(const float4*)pl; pC1 = *(const float4*)(pl + 4); pl += NN;
            pD0 = *(const float4*)pl; pD1 = *(const float4*)(pl + 4); pl += NN;
          } else {
            int r0 = (rown     < NN) ? rown     : NN - 1;
            int r1 = (rown + 1 < NN) ? rown + 1 : NN - 1;
            int r2 = (rown + 2 < NN) ? rown + 2 : NN - 1;
            int r3 = (rown + 3 < NN) ? rown + 3 : NN - 1;
            pA0 = *(const float4*)(src + (size_t)r0 * NN); pA1 = *(const float4*)(src + (size_t)r0 * NN + 4);
            pB0 = *(const float4*)(src + (size_t)r1 * NN); pB1 = *(const float4*)(src + (size_t)r1 * NN + 4);
            pC0 = *(const float4*)(src + (size_t)r2 * NN); pC1 = *(const float4*)(src + (size_t)r2 * NN + 4);
            pD0 = *(const float4*)(src + (size_t)r3 * NN); pD1 = *(const float4*)(src + (size_t)r3 * NN + 4);
            rown += 4;
          }
          rowF(a0, a1, kb + 0, kk == 0);
          rowF(b0, b1, kb + 1, false);
          rowF(c0v, c1v, kb + 2, false);
          rowF(d0, d1, kb + 3, false);
        }
        SinC = prevEdx * escale;
      }
      { // per-step shared-exponent rescale (32 rows)
        float m = tmx;
        m = fmaxf(m, __shfl_xor(m, 1));  m = fmaxf(m, __shfl_xor(m, 2));
        m = fmaxf(m, __shfl_xor(m, 4));  m = fmaxf(m, __shfl_xor(m, 8));
        m = fmaxf(m, __shfl_xor(m, 16)); m = fmaxf(m, __shfl_xor(m, 32));
        if (lane == 0) red[pr_][wv] = m;
      }
      __syncthreads();
      {
        float mm = red[pr_][lane & (NW - 1)];
        mm = fmaxf(mm, __shfl_xor(mm, 1));
        mm = fmaxf(mm, __shfl_xor(mm, 2));
        tmx = 0.f; escale = 1.f;
        int e = (mm > 0.f) ? ilogbf(mm) : 0;
        if (e > 126) e = 126; if (e < -126) e = -126;
        if (e != 0) {
          const float c = ldexpf(1.f, -e);
          s1_0*=c; s1_1*=c; s1_2*=c; s1_3*=c; s1_4*=c; s1_5*=c; s1_6*=c; s1_7*=c;
          tg0*=c; tg1*=c; tg2*=c; tg3*=c; tg4*=c; tg5*=c; tg6*=c; tg7*=c;
          yc0*=c; yc1*=c; yc2*=c; yc3*=c; yc4*=c; yc5*=c; yc6*=c; yc7*=c;
          acc*=c; one*=c; SinC*=c;
          escale = c; Etot += e;
        }
      }
    }
    float ssum = acc;
    ssum += __shfl_xor(ssum, 1);  ssum += __shfl_xor(ssum, 2);
    ssum += __shfl_xor(ssum, 4);  ssum += __shfl_xor(ssum, 8);
    ssum += __shfl_xor(ssum, 16); ssum += __shfl_xor(ssum, 32);
    if (lane == 0) wsum[wv] = ssum;
    __syncthreads();
    if (MODE == 0) {
      if (tid == 0) {
        double tot = 0.0;
        #pragma unroll
        for (int k = 0; k < NW; ++k) tot += (double)wsum[k];
        out[0] = (float)(log(tot) + (double)Etot * LN2);
      }
    } else {
      *(float4*)(arr + c0)              = make_float4(s1_0, s1_1, s1_2, s1_3);
      *(float4*)(arr + c0 + 4)          = make_float4(s1_4, s1_5, s1_6, s1_7);
      *(float4*)(arr + NN + c0)         = make_float4(tg0, tg1, tg2, tg3);
      *(float4*)(arr + NN + c0 + 4)     = make_float4(tg4, tg5, tg6, tg7);
      *(float4*)(arr + 2 * NN + c0)     = make_float4(yc0, yc1, yc2, yc3);
      *(float4*)(arr + 2 * NN + c0 + 4) = make_float4(yc4, yc5, yc6, yc7);
      if (tid == 0) {
        float t = 0.f;
        #pragma unroll
        for (int k = 0; k < NW; ++k) t += wsum[k];
        arr[5 * NN + 0] = t;                     // acc_top (units 2^E0)
        ((int*)(arr + 5 * NN))[2] = Etot;        // E0
      }
    }
  } else {
    // ======================= BACKWARD (adjoint, mirrored cols) =======================
    const int SPWB = 1024 / RPS;
    float gM0c=0.f,gM1c=0.f,gM2c=0.f,gM3c=0.f,gM4c=0.f,gM5c=0.f,gM6c=0.f,gM7c=0.f;
    float gY0c=0.f,gY1c=0.f,gY2c=0.f,gY3c=0.f,gY4c=0.f,gY5c=0.f,gY6c=0.f,gY7c=0.f;
    float accB=0.f, one=1.f, tmx=0.f, escale=1.f, gMinC=0.f;
    int Etot = 0;
    const float* src = tabR + c0;
    float4 pA0 = *(const float4*)(src),          pA1 = *(const float4*)(src + 4);
    float4 pB0 = *(const float4*)(src + NN),     pB1 = *(const float4*)(src + NN + 4);
    float4 pC0 = *(const float4*)(src + 2 * NN), pC1 = *(const float4*)(src + 2 * NN + 4);
    float4 pD0 = *(const float4*)(src + 3 * NN), pD1 = *(const float4*)(src + 3 * NN + 4);
    const float* pl = src + 4 * NN;

    int cr_ = 0, pr_ = 0;
    float prevEdx = 0.f;
    auto rowB = [&](float4 v0, float4 v1, int k, bool first) {
      const float e0 = v0.x, e1 = v0.y, e2 = v0.z, e3 = v0.w;
      const float e4 = v1.x, e5 = v1.y, e6 = v1.z, e7 = v1.w;
      const float2 edc = E[cr_][wv][k];
      const float gMdIn = first ? gMinC : prevEdx * escale;
      const float Xi = edc.y * escale;
      prevEdx = edc.x;

      float gmh  = __shfl_up(gM7c, 1);
      float gMd0 = isL0 ? gMdIn : gmh;
      accB = fmaf(e0, gMd0, accB); accB = fmaf(e1, gM0c, accB);
      accB = fmaf(e2, gM1c, accB); accB = fmaf(e3, gM2c, accB);
      accB = fmaf(e4, gM3c, accB); accB = fmaf(e5, gM4c, accB);
      accB = fmaf(e6, gM5c, accB); accB = fmaf(e7, gM6c, accB);
      float a0 = e0 * (gMd0 + one);
      float a1 = e1 * (gM0c + one);
      float a2 = e2 * (gM1c + one);
      float a3 = e3 * (gM2c + one);
      float a4 = e4 * (gM3c + one);
      float a5 = e5 * (gM4c + one);
      float a6 = e6 * (gM5c + one);
      float a7 = e7 * (gM6c + one);

      float gTs0 = fmaf(cGO, gY0c, a0);
      float gTs1 = fmaf(cGO, gY1c, a1);
      float gTs2 = fmaf(cGO, gY2c, a2);
      float gTs3 = fmaf(cGO, gY3c, a3);
      float gTs4 = fmaf(cGO, gY4c, a4);
      float gTs5 = fmaf(cGO, gY5c, a5);
      float gTs6 = fmaf(cGO, gY6c, a6);
      float gTs7 = fmaf(cGO, gY7c, a7);
      float gY0n = fmaf(cGE, gY0c, a0);
      float gY1n = fmaf(cGE, gY1c, a1);
      float gY2n = fmaf(cGE, gY2c, a2);
      float gY3n = fmaf(cGE, gY3c, a3);
      float gY4n = fmaf(cGE, gY4c, a4);
      float gY5n = fmaf(cGE, gY5c, a5);
      float gY6n = fmaf(cGE, gY6c, a6);
      float gY7n = fmaf(cGE, gY7c, a7);

      float Qg = fmaf(cGE, fmaf(cGE, fmaf(cGE, fmaf(cGE, fmaf(cGE, fmaf(cGE,
                 fmaf(cGE, gTs0, gTs1), gTs2), gTs3), gTs4), gTs5), gTs6), gTs7);
      float q1 = __shfl_up(Qg, 1);
      float q2 = __shfl_up(Qg, 2);
      q2 = isL1 ? Xi : q2;
      float gXin = fmaf(C8, q2, q1);
      gXin = isL0 ? Xi : gXin;
      float gX0 = fmaf(cGE, gXin, gTs0);
      float gX1 = fmaf(cGE, gX0,  gTs1);
      float gX2 = fmaf(cGE, gX1,  gTs2);
      float gX3 = fmaf(cGE, gX2,  gTs3);
      float gX4 = fmaf(cGE, gX3,  gTs4);
      float gX5 = fmaf(cGE, gX4,  gTs5);
      float gX6 = fmaf(cGE, gX5,  gTs6);
      float gM0n = fmaf(cGO, gXin, gTs0);
      float gM1n = fmaf(cGO, gX0,  gTs1);
      float gM2n = fmaf(cGO, gX1,  gTs2);
      float gM3n = fmaf(cGO, gX2,  gTs3);
      float gM4n = fmaf(cGO, gX3,  gTs4);
      float gM5n = fmaf(cGO, gX4,  gTs5);
      float gM6n = fmaf(cGO, gX5,  gTs6);
      float gM7n = fmaf(cGO, gX6,  gTs7);

      tmx = fmaxf(tmx, fmaxf(fmaxf(fmaxf(gM0n, gM1n), fmaxf(gM2n, gM3n)),
                             fmaxf(fmaxf(gM4n, gM5n), fmaxf(gM6n, gM7n))));
      tmx = fmaxf(tmx, fmaxf(fmaxf(fmaxf(gY0n, gY1n), fmaxf(gY2n, gY3n)),
                             fmaxf(fmaxf(gY4n, gY5n), fmaxf(gY6n, gY7n))));
      gM0c = gM0n; gM1c = gM1n; gM2c = gM2n; gM3c = gM3n;
      gM4c = gM4n; gM5c = gM5n; gM6c = gM6n; gM7c = gM7n;
      gY0c = gY0n; gY1c = gY1n; gY2c = gY2n; gY3c = gY3n;
      gY4c = gY4n; gY5c = gY5n; gY6c = gY6n; gY7c = gY7n;

      if (isL63) E[pr_][wv + 1][k] = make_float2(gM7n, fmaf(C8, gXin, Qg));
    };

    const int NSTEPB = SPWB + NW - 1 + 1;        // +1: epilogue row (es row 1024)
    for (int s = 0; s < NSTEPB; ++s) {
      pr_ = s & 1; cr_ = pr_ ^ 1;
      const bool actM = (s >= wv) && (s < wv + SPWB);
      const bool actE = (s == wv + SPWB);
      if (actM) {
        prevEdx = 0.f;
        for (int kk = 0; kk < RPS / 4; ++kk) {
          const int kb = kk << 2;
          float4 a0 = pA0, a1 = pA1, b0 = pB0, b1 = pB1;
          float4 c0v = pC0, c1v = pC1, d0 = pD0, d1 = pD1;
          pA0 = *(const float4*)pl; pA1 = *(const float4*)(pl + 4); pl += NN;
          pB0 = *(const float4*)pl; pB1 = *(const float4*)(pl + 4); pl += NN;
          pC0 = *(const float4*)pl; pC1 = *(const float4*)(pl + 4); pl += NN;
          pD0 = *(const float4*)pl; pD1 = *(const float4*)(pl + 4); pl += NN;
          rowB(a0, a1, kb + 0, kk == 0);
          rowB(b0, b1, kb + 1, false);
          rowB(c0v, c1v, kb + 2, false);
          rowB(d0, d1, kb + 3, false);
        }
        gMinC = prevEdx * escale;
      } else if (actE) {
        // epilogue: accB += es[1024,.] * gM[1024,.]  (tabR row 1024 = pA0/pA1)
        float gmh  = __shfl_up(gM7c, 1);
        float gMd0 = isL0 ? gMinC : gmh;
        accB = fmaf(pA0.x, gMd0, accB); accB = fmaf(pA0.y, gM0c, accB);
        accB = fmaf(pA0.z, gM1c, accB); accB = fmaf(pA0.w, gM2c, accB);
        accB = fmaf(pA1.x, gM3c, accB); accB = fmaf(pA1.y, gM4c, accB);
        accB = fmaf(pA1.z, gM5c, accB); accB = fmaf(pA1.w, gM6c, accB);
      }
      { // rescale (carries stay live to the end)
        float m = tmx;
        m = fmaxf(m, __shfl_xor(m, 1));  m = fmaxf(m, __shfl_xor(m, 2));
        m = fmaxf(m, __shfl_xor(m, 4));  m = fmaxf(m, __shfl_xor(m, 8));
        m = fmaxf(m, __shfl_xor(m, 16)); m = fmaxf(m, __shfl_xor(m, 32));
        if (lane == 0) red[pr_][wv] = m;
      }
      __syncthreads();
      {
        float mm = red[pr_][lane & (NW - 1)];
        mm = fmaxf(mm, __shfl_xor(mm, 1));
        mm = fmaxf(mm, __shfl_xor(mm, 2));
        tmx = 0.f; escale = 1.f;
        int e = (mm > 0.f) ? ilogbf(mm) : 0;
        if (e > 126) e = 126; if (e < -126) e = -126;
        if (e != 0) {
          const float c = ldexpf(1.f, -e);
          gM0c*=c; gM1c*=c; gM2c*=c; gM3c*=c; gM4c*=c; gM5c*=c; gM6c*=c; gM7c*=c;
          gY0c*=c; gY1c*=c; gY2c*=c; gY3c*=c; gY4c*=c; gY5c*=c; gY6c*=c; gY7c*=c;
          accB*=c; one*=c; gMinC*=c;
          escale = c; Etot += e;
        }
      }
    }
    // write gM[1024,b], gY[1024,b]  (b = 2047-c -> reversed, two float4s)
    *(float4*)(arr + 3 * NN + (2040 - c0)) = make_float4(gM7c, gM6c, gM5c, gM4c);
    *(float4*)(arr + 3 * NN + (2044 - c0)) = make_float4(gM3c, gM2c, gM1c, gM0c);
    *(float4*)(arr + 4 * NN + (2040 - c0)) = make_float4(gY7c, gY6c, gY5c, gY4c);
    *(float4*)(arr + 4 * NN + (2044 - c0)) = make_float4(gY3c, gY2c, gY1c, gY0c);
    float ssum = accB;
    ssum += __shfl_xor(ssum, 1);  ssum += __shfl_xor(ssum, 2);
    ssum += __shfl_xor(ssum, 4);  ssum += __shfl_xor(ssum, 8);
    ssum += __shfl_xor(ssum, 16); ssum += __shfl_xor(ssum, 32);
    if (lane == 0) wsum[wv] = ssum;
    __syncthreads();
    if (tid == 0) {
      float t = 0.f;
      #pragma unroll
      for (int k = 0; k < NW; ++k) t += wsum[k];
      arr[5 * NN + 1] = t;                       // acc_b0 (units 2^E1)
      ((int*)(arr + 5 * NN))[3] = Etot;          // E1
    }
  }
}

// ---------------------------------------------------------------------------
// Combine (unchanged): three exponent groups
//   A0 (2^E0) = acc_top + sum_b es[1024,b+1]*S[1023,b] ;  A1 (2^E1) = acc_b0
//   A01 (2^E0+E1) = sum_b es[1024,b+1]*gM[1024,b+1]*S[1023,b]
//                 + sum_b gY[1024,b]*(cGO*T[1023,b] + cGE*Y[1023,b])
// ---------------------------------------------------------------------------
__global__ __launch_bounds__(1024)
void combine_kernel(const float* __restrict__ tab, const float* __restrict__ arr,
                    float* __restrict__ out) {
  __shared__ double sh01[16], sh0[16];
  const int tid = threadIdx.x, lane = tid & 63, wv = tid >> 6;
  const float cGE = 0.36787944117144233f;
  double t01 = 0.0, t0 = 0.0;
  for (int b = tid; b < NN; b += 1024) {
    const float S  = arr[b];
    const float tg = arr[NN + b];
    const float yc = arr[2 * NN + b];
    const float gY = arr[4 * NN + b];
    t01 += (double)gY * ((double)tg + (double)cGE * (double)yc);
    if (b < NN - 1) {
      const float es = tab[(size_t)1024 * NN + b + 1];
      const float gM = arr[3 * NN + b + 1];
      t01 += (double)es * (double)gM * (double)S;
      t0  += (double)es * (double)S;
    }
  }
  #pragma unroll
  for (int off = 1; off < 64; off <<= 1) {
    t01 += __shfl_xor(t01, off);
    t0  += __shfl_xor(t0, off);
  }
  if (lane == 0) { sh01[wv] = t01; sh0[wv] = t0; }
  __syncthreads();
  if (tid == 0) {
    double A01 = 0.0, A0 = 0.0;
    #pragma unroll
    for (int k = 0; k < 16; ++k) { A01 += sh01[k]; A0 += sh0[k]; }
    const float* resF = arr + 5 * NN;
    const float accTop = resF[0], accB = resF[1];
    const int E0 = ((const int*)resF)[2], E1 = ((const int*)resF)[3];
    A0 += (double)accTop;
    const double A1 = (double)accB;
    const long long e01 = (long long)E0 + (long long)E1;
    long long em = e01;
    if ((long long)E0 > em) em = E0;
    if ((long long)E1 > em) em = E1;
    const double tot = A01 * exp2((double)(e01 - em))
                     + A0  * exp2((double)((long long)E0 - em))
                     + A1  * exp2((double)((long long)E1 - em));
    out[0] = (float)(log(tot) + (double)em * LN2);
  }
}

extern "C" void kernel_launch(void* const* d_in, const int* in_sizes, int n_in,
                              void* d_out, int out_size, void* d_ws, size_t ws_size,
                              hipStream_t stream) {
  const float* x = (const float*)d_in[0];
  float* out = (float*)d_out;
  const size_t need = ((size_t)2 * TROWS * NN + 5 * NN + 16) * sizeof(float);
  if (ws_size >= need) {
    float* tab  = (float*)d_ws;
    float* tabR = tab + (size_t)TROWS * NN;
    float* arr  = tab + (size_t)2 * TROWS * NN;
    prep_kernel<<<dim3(NN / 256, TROWS), dim3(256), 0, stream>>>(x, tab, tabR);
    sw2_kernel<1><<<dim3(2), dim3(NW * 64), 0, stream>>>(x, tab, tabR, arr, out);
    combine_kernel<<<dim3(1), dim3(1024), 0, stream>>>(tab, arr, out);
  } else {
    sw2_kernel<0><<<dim3(1), dim3(NW * 64), 0, stream>>>(x, nullptr, nullptr, nullptr, out);
  }
}

// Round 17
// 265.357 us; speedup vs baseline: 1.1136x; 1.1136x over previous
//
#include <hip/hip_runtime.h>
#include <hip/hip_bf16.h>
#include <math.h>

#define NN 2048           // x is 2048 x 2048 (DP grid = [0,2046]^2)
#define TROWS 1040        // table rows per half (1024 + prefetch margin)
#define NW 8              // 8 waves per WG (2 per SIMD), CPL=4  -- R14-proven optimum
#define RPS 32            // rows per wave per step (32-row cadence: ~57 nats << 88)
#define LN2 0.6931471805599453

// d_ws layout (floats): tab[TROWS][NN] | tabR[TROWS][NN] | arr: S,tg,yc,gM,gY (5*NN) | res (4 words)

__global__ void prep_kernel(const float* __restrict__ x, float* __restrict__ tab,
                            float* __restrict__ tabR) {
  const int c = blockIdx.x * 256 + threadIdx.x;
  const int t = blockIdx.y;
  tab[(size_t)t * NN + c] = __expf(x[(size_t)t * NN + c]);
  const int rr = 2048 - t, cc = 2048 - c;
  float v = 0.f;
  if (rr < 2048 && cc < 2048) v = __expf(x[(size_t)rr * NN + cc]);
  tabR[(size_t)t * NN + c] = v;
}

// ---------------------------------------------------------------------------
// R17 = R14 verbatim (best verified config after R15/R16 regressions).
// NW=8 waves (2/SIMD) x CPL=4, RPS=32, systolic skew, parity LDS edges,
// one barrier + one shared pow2 exponent per 32 rows, named prefetch regs
// (spill-proof, rule #20), bidirectional forward/adjoint split across 2
// independent WGs, exponent-aware combine.
// ---------------------------------------------------------------------------
template<int MODE>
__global__ __launch_bounds__(NW * 64)
void sw2_kernel(const float* __restrict__ x, const float* __restrict__ tab,
                const float* __restrict__ tabR, float* __restrict__ arr,
                float* __restrict__ out) {
  const int tid  = threadIdx.x;
  const int lane = tid & 63;
  const int wv   = __builtin_amdgcn_readfirstlane(tid >> 6);   // 0..7
  const int c0   = (wv << 8) + lane * 4;

  __shared__ float2 E[2][NW + 1][RPS];   // [parity][wave+1][row]; wave-0 input = zeros
  __shared__ float  red[2][NW];
  __shared__ float  wsum[NW];

  for (int i = tid; i < 2 * (NW + 1) * RPS; i += NW * 64)
    ((float2*)E)[i] = make_float2(0.f, 0.f);
  __syncthreads();

  const float cGO = 0.006737946999085467f;   // e^-5
  const float cGE = 0.36787944117144233f;    // e^-1
  const float C4  = 0.01831563888873418f;    // e^-4
  const bool isL0 = (lane == 0), isL1 = (lane == 1), isL63 = (lane == 63);

  if (MODE == 0 || blockIdx.x == 0) {
    // ======================= FORWARD =======================
    const int SPW   = ((MODE == 0) ? 2048 : 1024) / RPS;
    const int NSTEP = SPW + NW - 1;
    float s1_0=0.f,s1_1=0.f,s1_2=0.f,s1_3=0.f;
    float tg0=0.f,tg1=0.f,tg2=0.f,tg3=0.f;
    float yc0=0.f,yc1=0.f,yc2=0.f,yc3=0.f;
    float acc=0.f, one=1.f, tmx=0.f, escale=1.f, SinC=0.f;
    int Etot = 0;
    const float* src = ((MODE == 0) ? x : tab) + c0;
    float4 pfA = *(const float4*)(src);
    float4 pfB = *(const float4*)(src + NN);
    float4 pfC = *(const float4*)(src + 2 * NN);
    float4 pfD = *(const float4*)(src + 3 * NN);
    const float* pl = src + 4 * NN;
    int rown = 4;

    int cr_ = 0, pr_ = 0;
    float prevEdx = 0.f;
    auto rowF = [&](float4 ev, int k, bool first) {
      float ex0 = ev.x, ex1 = ev.y, ex2 = ev.z, ex3 = ev.w;
      if (MODE == 0) { ex0 = __expf(ex0); ex1 = __expf(ex1); ex2 = __expf(ex2); ex3 = __expf(ex3); }
      const float2 edc = E[cr_][wv][k];
      const float Sr = first ? SinC : prevEdx * escale;
      const float Xi = edc.y * escale;
      prevEdx = edc.x;

      float sh  = __shfl_up(s1_3, 1);
      float sd0 = isL0 ? Sr : sh;
      acc = fmaf(ex0, sd0,  acc);
      acc = fmaf(ex1, s1_0, acc);
      acc = fmaf(ex2, s1_1, acc);
      acc = fmaf(ex3, s1_2, acc);
      float M0 = ex0 * (sd0  + one);
      float M1 = ex1 * (s1_0 + one);
      float M2 = ex2 * (s1_1 + one);
      float M3 = ex3 * (s1_2 + one);

      float Q  = fmaf(cGE, fmaf(cGE, fmaf(cGE, M0, M1), M2), M3);
      float q1 = __shfl_up(Q, 1);
      float q2 = __shfl_up(Q, 2);
      q2 = isL1 ? Xi : q2;
      float X0 = fmaf(C4, q2, q1);
      X0 = isL0 ? Xi : X0;
      float X1 = fmaf(cGE, X0, M0);
      float X2 = fmaf(cGE, X1, M1);
      float X3 = fmaf(cGE, X2, M2);

      float T0 = fmaf(cGO, X0, M0);
      float T1 = fmaf(cGO, X1, M1);
      float T2 = fmaf(cGO, X2, M2);
      float T3 = fmaf(cGO, X3, M3);
      float Y0 = fmaf(cGE, yc0, tg0);
      float Y1 = fmaf(cGE, yc1, tg1);
      float Y2 = fmaf(cGE, yc2, tg2);
      float Y3 = fmaf(cGE, yc3, tg3);
      float S0 = T0 + Y0, S1n = T1 + Y1, S2n = T2 + Y2, S3n = T3 + Y3;
      tmx = fmaxf(tmx, fmaxf(fmaxf(S0, S1n), fmaxf(S2n, S3n)));
      tg0 = cGO * T0; tg1 = cGO * T1; tg2 = cGO * T2; tg3 = cGO * T3;
      yc0 = Y0; yc1 = Y1; yc2 = Y2; yc3 = Y3;
      s1_0 = S0; s1_1 = S1n; s1_2 = S2n; s1_3 = S3n;

      if (isL63) E[pr_][wv + 1][k] = make_float2(S3n, fmaf(C4, X0, Q));
    };

    for (int s = 0; s < NSTEP; ++s) {
      pr_ = s & 1; cr_ = pr_ ^ 1;
      const bool act = (s >= wv) && (s < wv + SPW);
      if (act) {
        prevEdx = 0.f;
        for (int kk = 0; kk < RPS / 4; ++kk) {
          const int kb = kk << 2;
          float4 e0 = pfA, e1 = pfB, e2 = pfC, e3 = pfD;
          if (MODE == 1) {
            pfA = *(const float4*)pl;          pl += NN;
            pfB = *(const float4*)pl;          pl += NN;
            pfC = *(const float4*)pl;          pl += NN;
            pfD = *(const float4*)pl;          pl += NN;
          } else {
            int r0 = (rown     < NN) ? rown     : NN - 1;
            int r1 = (rown + 1 < NN) ? rown + 1 : NN - 1;
            int r2 = (rown + 2 < NN) ? rown + 2 : NN - 1;
            int r3 = (rown + 3 < NN) ? rown + 3 : NN - 1;
            pfA = *(const float4*)(src + (size_t)r0 * NN);
            pfB = *(const float4*)(src + (size_t)r1 * NN);
            pfC = *(const float4*)(src + (size_t)r2 * NN);
            pfD = *(const float4*)(src + (size_t)r3 * NN);
            rown += 4;
          }
          rowF(e0, kb + 0, kk == 0);
          rowF(e1, kb + 1, false);
          rowF(e2, kb + 2, false);
          rowF(e3, kb + 3, false);
        }
        SinC = prevEdx * escale;
      }
      { // per-step shared-exponent rescale (32 rows)
        float m = tmx;
        m = fmaxf(m, __shfl_xor(m, 1));  m = fmaxf(m, __shfl_xor(m, 2));
        m = fmaxf(m, __shfl_xor(m, 4));  m = fmaxf(m, __shfl_xor(m, 8));
        m = fmaxf(m, __shfl_xor(m, 16)); m = fmaxf(m, __shfl_xor(m, 32));
        if (lane == 0) red[pr_][wv] = m;
      }
      __syncthreads();
      {
        float mm = red[pr_][lane & (NW - 1)];
        mm = fmaxf(mm, __shfl_xor(mm, 1));
        mm = fmaxf(mm, __shfl_xor(mm, 2));
        mm = fmaxf(mm, __shfl_xor(mm, 4));
        tmx = 0.f; escale = 1.f;
        int e = (mm > 0.f) ? ilogbf(mm) : 0;
        if (e > 126) e = 126; if (e < -126) e = -126;
        if (e != 0) {
          const float c = ldexpf(1.f, -e);
          s1_0*=c; s1_1*=c; s1_2*=c; s1_3*=c;
          tg0*=c; tg1*=c; tg2*=c; tg3*=c;
          yc0*=c; yc1*=c; yc2*=c; yc3*=c;
          acc*=c; one*=c; SinC*=c;
          escale = c; Etot += e;
        }
      }
    }
    float ssum = acc;
    ssum += __shfl_xor(ssum, 1);  ssum += __shfl_xor(ssum, 2);
    ssum += __shfl_xor(ssum, 4);  ssum += __shfl_xor(ssum, 8);
    ssum += __shfl_xor(ssum, 16); ssum += __shfl_xor(ssum, 32);
    if (lane == 0) wsum[wv] = ssum;
    __syncthreads();
    if (MODE == 0) {
      if (tid == 0) {
        double tot = 0.0;
        #pragma unroll
        for (int k = 0; k < NW; ++k) tot += (double)wsum[k];
        out[0] = (float)(log(tot) + (double)Etot * LN2);
      }
    } else {
      *(float4*)(arr + c0)          = make_float4(s1_0, s1_1, s1_2, s1_3);  // S[1023,b]
      *(float4*)(arr + NN + c0)     = make_float4(tg0, tg1, tg2, tg3);      // cGO*T[1023,b]
      *(float4*)(arr + 2 * NN + c0) = make_float4(yc0, yc1, yc2, yc3);      // Y[1023,b]
      if (tid == 0) {
        float t = 0.f;
        #pragma unroll
        for (int k = 0; k < NW; ++k) t += wsum[k];
        arr[5 * NN + 0] = t;                     // acc_top (units 2^E0)
        ((int*)(arr + 5 * NN))[2] = Etot;        // E0
      }
    }
  } else {
    // ======================= BACKWARD (adjoint, mirrored cols) =======================
    const int SPWB = 1024 / RPS;
    float gM1_0=0.f,gM1_1=0.f,gM1_2=0.f,gM1_3=0.f;
    float gY1_0=0.f,gY1_1=0.f,gY1_2=0.f,gY1_3=0.f;
    float accB=0.f, one=1.f, tmx=0.f, escale=1.f, gMinC=0.f;
    int Etot = 0;
    const float* src = tabR + c0;
    float4 pfA = *(const float4*)(src);
    float4 pfB = *(const float4*)(src + NN);
    float4 pfC = *(const float4*)(src + 2 * NN);
    float4 pfD = *(const float4*)(src + 3 * NN);
    const float* pl = src + 4 * NN;

    int cr_ = 0, pr_ = 0;
    float prevEdx = 0.f;
    auto rowB = [&](float4 ev, int k, bool first) {
      const float er0 = ev.x, er1 = ev.y, er2 = ev.z, er3 = ev.w;
      const float2 edc = E[cr_][wv][k];
      const float gMdIn = first ? gMinC : prevEdx * escale;
      const float Xi = edc.y * escale;
      prevEdx = edc.x;

      float gmh  = __shfl_up(gM1_3, 1);
      float gMd0 = isL0 ? gMdIn : gmh;
      float gMd1 = gM1_0, gMd2 = gM1_1, gMd3 = gM1_2;
      accB = fmaf(er0, gMd0, accB);
      accB = fmaf(er1, gMd1, accB);
      accB = fmaf(er2, gMd2, accB);
      accB = fmaf(er3, gMd3, accB);
      float a0 = er0 * (gMd0 + one);
      float a1 = er1 * (gMd1 + one);
      float a2 = er2 * (gMd2 + one);
      float a3 = er3 * (gMd3 + one);

      float gTs0 = fmaf(cGO, gY1_0, a0);
      float gTs1 = fmaf(cGO, gY1_1, a1);
      float gTs2 = fmaf(cGO, gY1_2, a2);
      float gTs3 = fmaf(cGO, gY1_3, a3);
      float gY0n = fmaf(cGE, gY1_0, a0);
      float gY1n = fmaf(cGE, gY1_1, a1);
      float gY2n = fmaf(cGE, gY1_2, a2);
      float gY3n = fmaf(cGE, gY1_3, a3);

      float Qg = fmaf(cGE, fmaf(cGE, fmaf(cGE, gTs0, gTs1), gTs2), gTs3);
      float q1 = __shfl_up(Qg, 1);
      float q2 = __shfl_up(Qg, 2);
      q2 = isL1 ? Xi : q2;
      float gXin = fmaf(C4, q2, q1);
      gXin = isL0 ? Xi : gXin;
      float gX0 = fmaf(cGE, gXin, gTs0);
      float gX1 = fmaf(cGE, gX0,  gTs1);
      float gX2 = fmaf(cGE, gX1,  gTs2);
      float gM0n = fmaf(cGO, gXin, gTs0);
      float gM1n = fmaf(cGO, gX0,  gTs1);
      float gM2n = fmaf(cGO, gX1,  gTs2);
      float gM3n = fmaf(cGO, gX2,  gTs3);

      tmx = fmaxf(tmx, fmaxf(fmaxf(gM0n, gM1n), fmaxf(gM2n, gM3n)));
      tmx = fmaxf(tmx, fmaxf(fmaxf(gY0n, gY1n), fmaxf(gY2n, gY3n)));
      gM1_0 = gM0n; gM1_1 = gM1n; gM1_2 = gM2n; gM1_3 = gM3n;
      gY1_0 = gY0n; gY1_1 = gY1n; gY1_2 = gY2n; gY1_3 = gY3n;

      if (isL63) E[pr_][wv + 1][k] = make_float2(gM3n, fmaf(C4, gXin, Qg));
    };

    const int NSTEPB = SPWB + NW - 1 + 1;        // +1: epilogue row (es row 1024)
    for (int s = 0; s < NSTEPB; ++s) {
      pr_ = s & 1; cr_ = pr_ ^ 1;
      const bool actM = (s >= wv) && (s < wv + SPWB);
      const bool actE = (s == wv + SPWB);
      if (actM) {
        prevEdx = 0.f;
        for (int kk = 0; kk < RPS / 4; ++kk) {
          const int kb = kk << 2;
          float4 e0 = pfA, e1 = pfB, e2 = pfC, e3 = pfD;
          pfA = *(const float4*)pl;            pl += NN;
          pfB = *(const float4*)pl;            pl += NN;
          pfC = *(const float4*)pl;            pl += NN;
          pfD = *(const float4*)pl;            pl += NN;
          rowB(e0, kb + 0, kk == 0);
          rowB(e1, kb + 1, false);
          rowB(e2, kb + 2, false);
          rowB(e3, kb + 3, false);
        }
        gMinC = prevEdx * escale;
      } else if (actE) {
        // epilogue: accB += es[1024,.] * gM[1024,.]  (tabR row 1024 = pfA)
        float gmh  = __shfl_up(gM1_3, 1);
        float gMd0 = isL0 ? gMinC : gmh;
        accB = fmaf(pfA.x, gMd0,  accB);
        accB = fmaf(pfA.y, gM1_0, accB);
        accB = fmaf(pfA.z, gM1_1, accB);
        accB = fmaf(pfA.w, gM1_2, accB);
      }
      { // rescale (carries stay live to the end)
        float m = tmx;
        m = fmaxf(m, __shfl_xor(m, 1));  m = fmaxf(m, __shfl_xor(m, 2));
        m = fmaxf(m, __shfl_xor(m, 4));  m = fmaxf(m, __shfl_xor(m, 8));
        m = fmaxf(m, __shfl_xor(m, 16)); m = fmaxf(m, __shfl_xor(m, 32));
        if (lane == 0) red[pr_][wv] = m;
      }
      __syncthreads();
      {
        float mm = red[pr_][lane & (NW - 1)];
        mm = fmaxf(mm, __shfl_xor(mm, 1));
        mm = fmaxf(mm, __shfl_xor(mm, 2));
        mm = fmaxf(mm, __shfl_xor(mm, 4));
        tmx = 0.f; escale = 1.f;
        int e = (mm > 0.f) ? ilogbf(mm) : 0;
        if (e > 126) e = 126; if (e < -126) e = -126;
        if (e != 0) {
          const float c = ldexpf(1.f, -e);
          gM1_0*=c; gM1_1*=c; gM1_2*=c; gM1_3*=c;
          gY1_0*=c; gY1_1*=c; gY1_2*=c; gY1_3*=c;
          accB*=c; one*=c; gMinC*=c;
          escale = c; Etot += e;
        }
      }
    }
    // write gM[1024,b], gY[1024,b]  (b = 2047-c -> reversed float4)
    *(float4*)(arr + 3 * NN + (2044 - c0)) = make_float4(gM1_3, gM1_2, gM1_1, gM1_0);
    *(float4*)(arr + 4 * NN + (2044 - c0)) = make_float4(gY1_3, gY1_2, gY1_1, gY1_0);
    float ssum = accB;
    ssum += __shfl_xor(ssum, 1);  ssum += __shfl_xor(ssum, 2);
    ssum += __shfl_xor(ssum, 4);  ssum += __shfl_xor(ssum, 8);
    ssum += __shfl_xor(ssum, 16); ssum += __shfl_xor(ssum, 32);
    if (lane == 0) wsum[wv] = ssum;
    __syncthreads();
    if (tid == 0) {
      float t = 0.f;
      #pragma unroll
      for (int k = 0; k < NW; ++k) t += wsum[k];
      arr[5 * NN + 1] = t;                       // acc_b0 (units 2^E1)
      ((int*)(arr + 5 * NN))[3] = Etot;          // E1
    }
  }
}

// ---------------------------------------------------------------------------
// Combine (unchanged): three exponent groups
//   A0 (2^E0) = acc_top + sum_b es[1024,b+1]*S[1023,b] ;  A1 (2^E1) = acc_b0
//   A01 (2^E0+E1) = sum_b es[1024,b+1]*gM[1024,b+1]*S[1023,b]
//                 + sum_b gY[1024,b]*(cGO*T[1023,b] + cGE*Y[1023,b])
// ---------------------------------------------------------------------------
__global__ __launch_bounds__(1024)
void combine_kernel(const float* __restrict__ tab, const float* __restrict__ arr,
                    float* __restrict__ out) {
  __shared__ double sh01[16], sh0[16];
  const int tid = threadIdx.x, lane = tid & 63, wv = tid >> 6;
  const float cGE = 0.36787944117144233f;
  double t01 = 0.0, t0 = 0.0;
  for (int b = tid; b < NN; b += 1024) {
    const float S  = arr[b];
    const float tg = arr[NN + b];
    const float yc = arr[2 * NN + b];
    const float gY = arr[4 * NN + b];
    t01 += (double)gY * ((double)tg + (double)cGE * (double)yc);
    if (b < NN - 1) {
      const float es = tab[(size_t)1024 * NN + b + 1];
      const float gM = arr[3 * NN + b + 1];
      t01 += (double)es * (double)gM * (double)S;
      t0  += (double)es * (double)S;
    }
  }
  #pragma unroll
  for (int off = 1; off < 64; off <<= 1) {
    t01 += __shfl_xor(t01, off);
    t0  += __shfl_xor(t0, off);
  }
  if (lane == 0) { sh01[wv] = t01; sh0[wv] = t0; }
  __syncthreads();
  if (tid == 0) {
    double A01 = 0.0, A0 = 0.0;
    #pragma unroll
    for (int k = 0; k < 16; ++k) { A01 += sh01[k]; A0 += sh0[k]; }
    const float* resF = arr + 5 * NN;
    const float accTop = resF[0], accB = resF[1];
    const int E0 = ((const int*)resF)[2], E1 = ((const int*)resF)[3];
    A0 += (double)accTop;
    const double A1 = (double)accB;
    const long long e01 = (long long)E0 + (long long)E1;
    long long em = e01;
    if ((long long)E0 > em) em = E0;
    if ((long long)E1 > em) em = E1;
    const double tot = A01 * exp2((double)(e01 - em))
                     + A0  * exp2((double)((long long)E0 - em))
                     + A1  * exp2((double)((long long)E1 - em));
    out[0] = (float)(log(tot) + (double)em * LN2);
  }
}

extern "C" void kernel_launch(void* const* d_in, const int* in_sizes, int n_in,
                              void* d_out, int out_size, void* d_ws, size_t ws_size,
                              hipStream_t stream) {
  const float* x = (const float*)d_in[0];
  float* out = (float*)d_out;
  const size_t need = ((size_t)2 * TROWS * NN + 5 * NN + 16) * sizeof(float);
  if (ws_size >= need) {
    float* tab  = (float*)d_ws;
    float* tabR = tab + (size_t)TROWS * NN;
    float* arr  = tab + (size_t)2 * TROWS * NN;
    prep_kernel<<<dim3(NN / 256, TROWS), dim3(256), 0, stream>>>(x, tab, tabR);
    sw2_kernel<1><<<dim3(2), dim3(NW * 64), 0, stream>>>(x, tab, tabR, arr, out);
    combine_kernel<<<dim3(1), dim3(1024), 0, stream>>>(tab, arr, out);
  } else {
    sw2_kernel<0><<<dim3(1), dim3(NW * 64), 0, stream>>>(x, nullptr, nullptr, nullptr, out);
  }
}